// Round 5
// baseline (3722.476 us; speedup 1.0000x reference)
//
#include <hip/hip_runtime.h>

typedef unsigned short ushort_t;
typedef __attribute__((ext_vector_type(8))) __bf16 bf16x8;
typedef __attribute__((ext_vector_type(8))) unsigned short us8;
typedef __attribute__((ext_vector_type(4))) float f32x4;

#define BATCH 64
#define HDIM 1024
#define TDIM 64
#define DDIM 256
#define NCELL 384

// workspace layout (bytes)
#define SW_OFF   0ull
#define SWF_OFF  94371840ull
#define HB_OFF   94896128ull
#define TOPS_OFF 95682560ull
#define CST_OFF  104071168ull
#define XC_OFF   104857600ull
#define PAR_OFF  106954752ull
#define FLAG_OFF 107176960ull
#define WS_NEED  107177088ull

// canonical fp32 param block offsets (floats)
#define P_BIAS 0
#define P_WC   24576
#define P_FB   49152
#define P_H0   49408
#define P_C0   52480
#define P_TOT  55552

struct PtrPack { const void* p[17]; };

// element counts of the 17 tensor inputs (dict order)
__device__ const int g_ecnt[17] = {
  1048576,  // x
  1048576,  // enc_Wx0
  4194304,  // enc_Wh0
  4096,     // enc_Wc0
  4096,     // enc_b0
  8388608,  // enc_Wx
  8388608,  // enc_Wh
  8192,     // enc_Wc
  8192,     // enc_b
  12582912, // dec_Wx
  12582912, // dec_Wh
  12288,    // dec_Wc
  12288,    // dec_b
  262144,   // fin_W
  256,      // fin_b
  3072,     // h0
  3072      // c0
};

__device__ __forceinline__ float b2f(ushort_t u) {
  union { unsigned i; float f; } v; v.i = ((unsigned)u) << 16; return v.f;
}
__device__ __forceinline__ ushort_t f2b(float f) {
  union { float f; unsigned i; } v; v.f = f;
  unsigned r = v.i + 0x7FFFu + ((v.i >> 16) & 1u);
  return (ushort_t)(r >> 16);
}
__device__ __forceinline__ float sigm(float x) { return 1.0f / (1.0f + __expf(-x)); }
__device__ __forceinline__ float tanh_f(float x) { return 1.0f - 2.0f / (__expf(2.0f * x) + 1.0f); }

// dtype-aware element load -> fp32 / bf16
__device__ __forceinline__ float ldf(const void* p, size_t i, int f32) {
  return f32 ? ((const float*)p)[i] : b2f(((const ushort_t*)p)[i]);
}
__device__ __forceinline__ ushort_t ldu(const void* p, size_t i, int f32) {
  return f32 ? f2b(((const float*)p)[i]) : ((const ushort_t*)p)[i];
}

__global__ void zeroflags_k(int* flags) {
  if (threadIdx.x < 17) flags[threadIdx.x] = 0;
}

// ---- per-tensor dtype detection. True bf16 data here has |v| < 2^17 ->
// exponent < 0x90 always; fp32 storage puts mantissa garbage in the low
// halfword -> ~uniform exponent field -> P(>=0x90)=0.44 per sample.
__global__ void detect_k(PtrPack pk, int* flags) {
  const int t = blockIdx.x;
  const ushort_t* u = (const ushort_t*)pk.p[t];
  const int n = g_ecnt[t];
  int bad = 0;
  int i = threadIdx.x;
  for (int it = 0; i < n && it < 256; i += 256, ++it) {
    unsigned e = (u[i] >> 7) & 0xFFu;
    if (e >= 0x90u) bad = 1;
  }
  if (bad) atomicOr(&flags[t], 1);
}

// ---- canonicalize small params to fp32 block (per-tensor dtype)
__global__ void canon_par_k(PtrPack pk, float* __restrict__ par,
                            const int* __restrict__ flags) {
  const int idx = blockIdx.x * 256 + threadIdx.x;
  if (idx >= P_TOT) return;
  int src; size_t off;
  if (idx < P_WC) {                       // biases: eb0, eb[0..1], db[0..2]
    const int lm = idx >> 12, r = idx & 4095;
    if (lm == 0)      { src = 4;  off = r; }
    else if (lm <= 2) { src = 8;  off = (size_t)(lm - 1) * 4096 + r; }
    else              { src = 12; off = (size_t)(lm - 3) * 4096 + r; }
  } else if (idx < P_FB) {                // Wc: eWc0, eWc[0..1], dWc[0..2]
    const int t = idx - P_WC, lm = t >> 12, r = t & 4095;
    if (lm == 0)      { src = 3;  off = r; }
    else if (lm <= 2) { src = 7;  off = (size_t)(lm - 1) * 4096 + r; }
    else              { src = 11; off = (size_t)(lm - 3) * 4096 + r; }
  } else if (idx < P_H0) { src = 14; off = idx - P_FB; }
  else if (idx < P_C0)   { src = 15; off = idx - P_H0; }
  else                   { src = 16; off = idx - P_C0; }
  par[idx] = ldf(pk.p[src], off, flags[src]);
}

// ---- canonicalize x to bf16
__global__ void canon_x_k(const void* x, ushort_t* __restrict__ xc,
                          const int* __restrict__ flag) {
  const int f32 = flag[0];
  const int idx = blockIdx.x * 256 + threadIdx.x;   // exactly 64*64*256
  xc[idx] = ldu(x, idx, f32);
}

// ---- init: c-state (fp32) and parity-1 h buffers, from canonical params
__global__ void init_k(const float* __restrict__ par,
                       ushort_t* __restrict__ hbg, float* __restrict__ cst) {
  const int idx = blockIdx.x * 256 + threadIdx.x;   // < 3*64*1024
  const int l = idx >> 16;
  const int rn = idx & 65535;
  const int n = idx & 1023;
  cst[idx] = par[P_C0 + l * 1024 + n];
  hbg[(3 + l) * (BATCH * HDIM) + rn] = f2b(par[P_H0 + l * 1024 + n]);
}

// ---- weight swizzle into MFMA-B-fragment order: SW[layer][g*2+ct][kt][lane][8]
__global__ void swizzle_k(PtrPack pk, ushort_t* __restrict__ SW,
                          ushort_t* __restrict__ SWF, const int* __restrict__ flags)
{
  const int seg = blockIdx.y;
  const int cid = blockIdx.x * 256 + threadIdx.x;
  const int lane = cid & 63;
  const int nidx = lane & 15;
  const int kg8 = (lane >> 4) << 3;
  if (seg == 6) {  // fin_W (1024x256) -> SWF[ct][kt][lane][8]
    if (cid >= 32768) return;
    const int f32 = flags[13];
    const void* fW = pk.p[13];
    const int c2 = cid >> 6;
    const int kt = c2 & 31;
    const int ct = c2 >> 5;
    const int n = ct * 16 + nidx;
    us8 v;
#pragma unroll
    for (int e = 0; e < 8; ++e) v[e] = ldu(fW, (size_t)(kt * 32 + kg8 + e) * 256 + n, f32);
    *(us8*)(SWF + ((size_t)(ct * 32 + kt)) * 512 + lane * 8) = v;
    return;
  }
  const int Kx  = (seg == 0) ? 256 : 1024;
  const int Ktf = (seg == 0) ? 40 : 64;
  if (cid >= 16384 * Ktf) return;
  const int c2 = cid >> 6;
  const int kt = c2 % Ktf;
  const int c3 = c2 / Ktf;        // g*2 + ct
  const int ct = c3 & 1;
  const int g  = c3 >> 1;
  const int p  = ct * 16 + nidx;  // packed col 0..31: [f0..7 i0..7 | g0..7 o0..7]
  const int zcol = (p >> 3) * 1024 + g * 8 + (p & 7);
  int sx, sh; size_t wxo;
  switch (seg) {
    case 0:  sx = 1; sh = 2;  wxo = 0;        break;
    case 1:  sx = 5; sh = 6;  wxo = 0;        break;
    case 2:  sx = 5; sh = 6;  wxo = 4194304;  break;
    case 3:  sx = 9; sh = 10; wxo = 0;        break;
    case 4:  sx = 9; sh = 10; wxo = 4194304;  break;
    default: sx = 9; sh = 10; wxo = 8388608;  break;
  }
  const void* Wx = pk.p[sx]; const void* Wh = pk.p[sh];
  const int fx = flags[sx], fh = flags[sh];
  const size_t wbase = (seg == 0) ? 0ull : (5242880ull + (size_t)(seg - 1) * 8388608ull);
  us8 v;
#pragma unroll
  for (int e = 0; e < 8; ++e) {
    const int k = kt * 32 + kg8 + e;
    v[e] = (k < Kx) ? ldu(Wx, wxo + (size_t)k * 4096 + zcol, fx)
                    : ldu(Wh, wxo + (size_t)(k - Kx) * 4096 + zcol, fh);
  }
  *(us8*)(SW + wbase + ((size_t)c3 * Ktf + kt) * 512 + (size_t)lane * 8) = v;
}

// ---- one LSTM cell: grid 256 WGs x 256 thr, stream-ordered
__global__ __launch_bounds__(256) void cell_k(int cell,
    const ushort_t* __restrict__ xc, const float* __restrict__ par,
    const ushort_t* __restrict__ SW,
    ushort_t* __restrict__ hbg, ushort_t* __restrict__ tops, float* __restrict__ cst)
{
  __shared__ float zred[4][32][33];

  const int tid  = threadIdx.x;
  const int w4   = tid >> 6;
  const int lane = tid & 63;
  const int ml   = lane & 15;
  const int kg8  = (lane >> 4) << 3;
  const int g    = blockIdx.x & 127;   // col-group: 8 h-cols -> 32 packed z-cols
  const int rg   = blockIdx.x >> 7;    // row-group: 32 batch rows
  const int m0   = rg * 32;

  int u, layer, lmat;
  if (cell < 192) { u = cell / 3; layer = cell - u * 3; lmat = layer; }
  else { int c2 = cell - 192; int s = c2 / 3; layer = c2 - s * 3; u = 64 + s; lmat = layer + 3; }
  const int pw = u & 1, pr = pw ^ 1;
  ushort_t* hw = hbg + (size_t)(pw * 3 + layer) * (BATCH * HDIM);
  const ushort_t* hp = hbg + (size_t)(pr * 3 + layer) * (BATCH * HDIM);
  const ushort_t* xs; int xstride, xoff;
  if (lmat == 0)      { xs = xc; xstride = TDIM * DDIM; xoff = u * DDIM; }
  else if (lmat == 3) { xs = hbg + (size_t)(pr * 3 + 2) * (BATCH * HDIM); xstride = HDIM; xoff = 0; }
  else                { xs = hbg + (size_t)(pw * 3 + (layer - 1)) * (BATCH * HDIM); xstride = HDIM; xoff = 0; }
  const int Kxl = (lmat == 0) ? 256 : 1024;
  const int Ktf = (lmat == 0) ? 40 : 64;
  const int Kt4 = Ktf >> 2;
  const int ktbase = w4 * Kt4;
  const size_t wbase = (lmat == 0) ? 0ull : (5242880ull + (size_t)(lmat - 1) * 8388608ull);
  const ushort_t* wp0 = SW + wbase + ((size_t)(g * 2) * Ktf + ktbase) * 512 + lane * 8;
  const ushort_t* wp1 = wp0 + (size_t)Ktf * 512;
  const ushort_t* axb = xs + (size_t)(m0 + ml) * xstride + xoff + kg8;
  const ushort_t* ahb = hp + (size_t)(m0 + ml) * HDIM + kg8;
  const size_t ax16 = (size_t)16 * xstride;

  f32x4 a00 = {0,0,0,0}, a01 = {0,0,0,0}, a10 = {0,0,0,0}, a11 = {0,0,0,0};
#pragma unroll 2
  for (int kt = 0; kt < Kt4; ++kt) {
    const int k0 = (ktbase + kt) << 5;
    const ushort_t* ap; size_t r16;
    if (k0 < Kxl) { ap = axb + k0; r16 = ax16; }
    else          { ap = ahb + (k0 - Kxl); r16 = (size_t)(16 * HDIM); }
    bf16x8 A0 = __builtin_bit_cast(bf16x8, *(const us8*)ap);
    bf16x8 A1 = __builtin_bit_cast(bf16x8, *(const us8*)(ap + r16));
    bf16x8 B0 = __builtin_bit_cast(bf16x8, *(const us8*)wp0); wp0 += 512;
    bf16x8 B1 = __builtin_bit_cast(bf16x8, *(const us8*)wp1); wp1 += 512;
    a00 = __builtin_amdgcn_mfma_f32_16x16x32_bf16(A0, B0, a00, 0, 0, 0);
    a10 = __builtin_amdgcn_mfma_f32_16x16x32_bf16(A1, B0, a10, 0, 0, 0);
    a01 = __builtin_amdgcn_mfma_f32_16x16x32_bf16(A0, B1, a01, 0, 0, 0);
    a11 = __builtin_amdgcn_mfma_f32_16x16x32_bf16(A1, B1, a11, 0, 0, 0);
  }
  {
    const int q4 = (lane >> 4) << 2;
#pragma unroll
    for (int i = 0; i < 4; ++i) {
      zred[w4][q4 + i][ml]           = a00[i];
      zred[w4][q4 + i][16 + ml]      = a01[i];
      zred[w4][16 + q4 + i][ml]      = a10[i];
      zred[w4][16 + q4 + i][16 + ml] = a11[i];
    }
  }
  __syncthreads();
  {
    const int row = tid >> 3, j = tid & 7, n = g * 8 + j;
    float zf = 0, zi = 0, zg = 0, zo = 0;
#pragma unroll
    for (int wv = 0; wv < 4; ++wv) {
      zf += zred[wv][row][j];
      zi += zred[wv][row][8 + j];
      zg += zred[wv][row][16 + j];
      zo += zred[wv][row][24 + j];
    }
    const float* bias = par + P_BIAS + lmat * 4096;
    const float* wc   = par + P_WC   + lmat * 4096;
    const size_t ci = ((size_t)layer * 64 + m0 + row) * 1024 + n;
    const float cprev = cst[ci];
    zf += bias[n]        + wc[n] * cprev;
    zi += bias[1024 + n] + wc[1024 + n] * cprev;
    zg += bias[2048 + n] + wc[2048 + n] * cprev;
    zo += bias[3072 + n] + wc[3072 + n] * cprev;
    const float fgt = sigm(zf), igt = sigm(zi), ggt = tanh_f(zg), ogt = sigm(zo);
    const float cn = fgt * cprev + igt * ggt;
    const float hh = ogt * tanh_f(cn);
    cst[ci] = cn;
    const ushort_t hb16 = f2b(hh);
    hw[(size_t)(m0 + row) * HDIM + n] = hb16;
    if (lmat == 5) tops[((size_t)(u - 64) * BATCH + m0 + row) * HDIM + n] = hb16;
  }
}

// ---- final projection: out = sigmoid(tops @ fin_W + fin_b)  [fp32 output!]
__global__ __launch_bounds__(256) void final_k(const ushort_t* __restrict__ SWF,
                                               const float* __restrict__ par,
                                               const ushort_t* __restrict__ tops,
                                               float* __restrict__ out)
{
  const int tid  = threadIdx.x;
  const int w4   = tid >> 6;
  const int lane = tid & 63;
  const int ml   = lane & 15;
  const int kg8  = (lane >> 4) << 3;
  const int mrow0 = blockIdx.x * 16;
  const ushort_t* ta = tops + (size_t)(mrow0 + ml) * HDIM + kg8;
  f32x4 acc0 = {0,0,0,0}, acc1 = {0,0,0,0}, acc2 = {0,0,0,0}, acc3 = {0,0,0,0};
  const ushort_t* b0p = SWF + ((size_t)(w4 * 4 + 0) * 32) * 512 + lane * 8;
  const ushort_t* b1p = b0p + 32 * 512;
  const ushort_t* b2p = b0p + 64 * 512;
  const ushort_t* b3p = b0p + 96 * 512;
#pragma unroll 4
  for (int kt = 0; kt < 32; ++kt) {
    bf16x8 A  = __builtin_bit_cast(bf16x8, *(const us8*)(ta + kt * 32));
    bf16x8 B0 = __builtin_bit_cast(bf16x8, *(const us8*)(b0p + kt * 512));
    bf16x8 B1 = __builtin_bit_cast(bf16x8, *(const us8*)(b1p + kt * 512));
    bf16x8 B2 = __builtin_bit_cast(bf16x8, *(const us8*)(b2p + kt * 512));
    bf16x8 B3 = __builtin_bit_cast(bf16x8, *(const us8*)(b3p + kt * 512));
    acc0 = __builtin_amdgcn_mfma_f32_16x16x32_bf16(A, B0, acc0, 0, 0, 0);
    acc1 = __builtin_amdgcn_mfma_f32_16x16x32_bf16(A, B1, acc1, 0, 0, 0);
    acc2 = __builtin_amdgcn_mfma_f32_16x16x32_bf16(A, B2, acc2, 0, 0, 0);
    acc3 = __builtin_amdgcn_mfma_f32_16x16x32_bf16(A, B3, acc3, 0, 0, 0);
  }
  const int q4 = (lane >> 4) << 2;
  f32x4 accs[4] = {acc0, acc1, acc2, acc3};
#pragma unroll
  for (int cc = 0; cc < 4; ++cc) {
    const int col = (w4 * 4 + cc) * 16 + ml;
    const float bbv = par[P_FB + col];
#pragma unroll
    for (int i = 0; i < 4; ++i) {
      const float v = sigm(accs[cc][i] + bbv);
      out[(size_t)(mrow0 + q4 + i) * 256 + col] = v;
    }
  }
}

extern "C" void kernel_launch(void* const* d_in, const int* in_sizes, int n_in,
                              void* d_out, int out_size, void* d_ws, size_t ws_size,
                              hipStream_t stream) {
  if (ws_size < WS_NEED) return;  // workspace too small for this design
  PtrPack pk;
  for (int i = 0; i < 17; ++i) pk.p[i] = d_in[i];
  char* ws = (char*)d_ws;
  ushort_t* SW  = (ushort_t*)(ws + SW_OFF);
  ushort_t* SWF = (ushort_t*)(ws + SWF_OFF);
  ushort_t* hb  = (ushort_t*)(ws + HB_OFF);
  ushort_t* tp  = (ushort_t*)(ws + TOPS_OFF);
  float*    cst = (float*)(ws + CST_OFF);
  ushort_t* xcn = (ushort_t*)(ws + XC_OFF);
  float*    par = (float*)(ws + PAR_OFF);
  int*      flg = (int*)(ws + FLAG_OFF);

  hipLaunchKernelGGL(zeroflags_k, dim3(1), dim3(32), 0, stream, flg);
  hipLaunchKernelGGL(detect_k, dim3(17), dim3(256), 0, stream, pk, flg);
  hipLaunchKernelGGL(canon_par_k, dim3(224), dim3(256), 0, stream, pk, par, (const int*)flg);
  hipLaunchKernelGGL(canon_x_k, dim3(4096), dim3(256), 0, stream, d_in[0], xcn, (const int*)flg);
  hipLaunchKernelGGL(swizzle_k, dim3(4096, 7), dim3(256), 0, stream, pk, SW, SWF, (const int*)flg);
  hipLaunchKernelGGL(init_k, dim3(768), dim3(256), 0, stream, (const float*)par, hb, cst);
  for (int cell = 0; cell < NCELL; ++cell) {
    hipLaunchKernelGGL(cell_k, dim3(256), dim3(256), 0, stream, cell,
                       (const ushort_t*)xcn, (const float*)par,
                       (const ushort_t*)SW, hb, tp, cst);
  }
  hipLaunchKernelGGL(final_k, dim3(256), dim3(256), 0, stream,
                     (const ushort_t*)SWF, (const float*)par, (const ushort_t*)tp,
                     (float*)d_out);
}